// Round 19
// baseline (369.455 us; speedup 1.0000x reference)
//
#include <hip/hip_runtime.h>

#define DIM   1024
#define HID   2048
#define NE    8
#define T_TOK 4096

typedef __attribute__((ext_vector_type(8))) short short8;
typedef __attribute__((ext_vector_type(4))) float f32x4;

__device__ __forceinline__ ushort f2bf(float f) {
    union { float f; unsigned u; } v; v.f = f;
    unsigned r = v.u + 0x7FFFu + ((v.u >> 16) & 1u);   // RNE
    return (ushort)(r >> 16);
}

// tanh-form gelu, x - x/(e+1) (inf-safe); dev from erf-gelu ~1e-3, absorbed by bf16.
__device__ __forceinline__ float gelu_fast(float x) {
    float t = x * x;
    float u = x * (1.0f + 0.044715f * t);
    float e = exp2f(2.3020585f * u);
    return x - x / (e + 1.0f);
}

// ------- transpose+convert, all 18 weight matrices in one launch (verified R13/R15) -------
__global__ __launch_bounds__(256)
void transpose_conv18(const float* __restrict__ ew1, const float* __restrict__ sw1,
                      const float* __restrict__ ew2, const float* __restrict__ sw2,
                      ushort* __restrict__ ew1T, ushort* __restrict__ sw1T,
                      ushort* __restrict__ ew2T, ushort* __restrict__ sw2T) {
    __shared__ float tile[64][65];
    int z = blockIdx.z;
    const float* in; ushort* out; int R, C, bx, by;
    if (z < 9) {
        R = DIM; C = HID; bx = blockIdx.x; by = blockIdx.y;              // 32 x 16
        in  = (z < 8) ? ew1  + (size_t)z * R * C : sw1;
        out = (z < 8) ? ew1T + (size_t)z * R * C : sw1T;
    } else {
        int zz = z - 9;
        R = HID; C = DIM;
        bx = blockIdx.x & 15; by = blockIdx.y * 2 + (blockIdx.x >> 4);   // 16 x 32
        in  = (zz < 8) ? ew2  + (size_t)zz * R * C : sw2;
        out = (zz < 8) ? ew2T + (size_t)zz * R * C : sw2T;
    }
    int c0 = bx * 64, r0 = by * 64;
    int t = threadIdx.x;
    int lr = t >> 4, lc4 = (t & 15) * 4;
#pragma unroll
    for (int p = 0; p < 4; ++p) {
        float4 f = *(const float4*)(in + (size_t)(r0 + p * 16 + lr) * C + c0 + lc4);
        tile[p * 16 + lr][lc4]     = f.x;
        tile[p * 16 + lr][lc4 + 1] = f.y;
        tile[p * 16 + lr][lc4 + 2] = f.z;
        tile[p * 16 + lr][lc4 + 3] = f.w;
    }
    __syncthreads();
    int oc = t >> 3, rg = (t & 7) * 8;
#pragma unroll
    for (int p = 0; p < 2; ++p) {
        int c = p * 32 + oc;
        short8 o;
#pragma unroll
        for (int j = 0; j < 8; ++j) o[j] = (short)f2bf(tile[rg + j][c]);
        *(short8*)(out + (size_t)(c0 + c) * R + r0 + rg) = o;
    }
}

// ---- router (+ x->bf16 convert fused): top-2 of softmax(x@rw+rb), renormalized ----
__global__ void router_kernel(const float* __restrict__ x, const float* __restrict__ rw,
                              const float* __restrict__ rb, int* __restrict__ cnt,
                              int* __restrict__ ids, float* __restrict__ wts,
                              int* __restrict__ te, int* __restrict__ tp,
                              ushort* __restrict__ xb) {
    int wave = threadIdx.x >> 6;
    int lane = threadIdx.x & 63;
    int t = blockIdx.x * 4 + wave;
    const float* xr = x + (size_t)t * DIM;
    ushort* xo = xb + (size_t)t * DIM;
    float acc[NE];
#pragma unroll
    for (int e = 0; e < NE; ++e) acc[e] = 0.f;
    {
        int d0 = lane * 16;
        float v[16];
#pragma unroll
        for (int j = 0; j < 16; j += 4) {
            float4 f = *(const float4*)(xr + d0 + j);
            v[j] = f.x; v[j+1] = f.y; v[j+2] = f.z; v[j+3] = f.w;
        }
        short8 o0, o1;
#pragma unroll
        for (int j = 0; j < 8; ++j) { o0[j] = (short)f2bf(v[j]); o1[j] = (short)f2bf(v[8+j]); }
        *(short8*)(xo + d0)     = o0;
        *(short8*)(xo + d0 + 8) = o1;
#pragma unroll
        for (int j = 0; j < 16; ++j) {
#pragma unroll
            for (int e = 0; e < NE; ++e) acc[e] += v[j] * rw[(d0 + j) * NE + e];
        }
    }
#pragma unroll
    for (int e = 0; e < NE; ++e) {
#pragma unroll
        for (int off = 32; off; off >>= 1) acc[e] += __shfl_xor(acc[e], off);
    }
    if (lane == 0) {
        float l[NE];
#pragma unroll
        for (int e = 0; e < NE; ++e) l[e] = acc[e] + rb[e];
        int i1 = 0;
#pragma unroll
        for (int e = 1; e < NE; ++e) if (l[e] > l[i1]) i1 = e;
        int i2 = (i1 == 0) ? 1 : 0;
#pragma unroll
        for (int e = 0; e < NE; ++e) if (e != i1 && l[e] > l[i2]) i2 = e;
        float p2 = __expf(l[i2] - l[i1]);      // p1 = 1
        float w1 = 1.0f / (1.0f + p2);
        float w2 = p2 / (1.0f + p2);
        int pos1 = atomicAdd(&cnt[i1], 1);
        ids[i1 * T_TOK + pos1] = t; wts[i1 * T_TOK + pos1] = w1;
        te[2 * t] = i1; tp[2 * t] = pos1;
        int pos2 = atomicAdd(&cnt[i2], 1);
        ids[i2 * T_TOK + pos2] = t; wts[i2 * T_TOK + pos2] = w2;
        te[2 * t + 1] = i2; tp[2 * t + 1] = pos2;
    }
}

// ------- build offsets + work queues.
// q1 (gemm1, 128x128): z -> nt -> mt order, so consecutive items share the 256 KB
//    B panel (z,nt); consumed by 8 XCD-partitioned cursors (nq[8..15]) — R18 proven
//    (FETCH 177->68 MB).
// q2 (gemm2, 256x256): mt-outer (R11 proven). item = (z<<16)|(mt<<8)|nt. -------
__global__ void build_queue(const int* __restrict__ cnt, int* __restrict__ offs,
                            int* __restrict__ q1, int* __restrict__ q2,
                            int* __restrict__ nq) {
    if (threadIdx.x != 0) return;
    int s = 0;
    for (int e = 0; e < NE; ++e) { offs[e] = s; s += cnt[e]; }
    int k1 = 0, k2 = 0;
    for (int z = 0; z <= NE; ++z) {
        int c = (z < NE) ? cnt[z] : T_TOK;
        int mts1 = (c + 127) >> 7;
        for (int nt = 0; nt < HID / 128; ++nt)
            for (int mt = 0; mt < mts1; ++mt)
                q1[k1++] = (z << 16) | (mt << 8) | nt;
        int mts2 = (c + 255) >> 8;
        for (int mt = 0; mt < mts2; ++mt)
            for (int nt = 0; nt < DIM / 256; ++nt)
                q2[k2++] = (z << 16) | (mt << 8) | nt;
    }
    nq[0] = k1; nq[1] = k2;
    for (int i = 2; i < 16; ++i) nq[i] = 0;    // cursors (8 partition cursors at 8..15)
}

// ===== GEMM1 inner: m97 structure, 128x128, BK=64, 4 waves, 32 KiB single-buffer =====
__device__ __forceinline__ void mma_tile(
    const ushort* __restrict__ A, const int* __restrict__ gather, int count,
    const ushort* __restrict__ BT, int K, int tileM, int tileN,
    ushort* lds, f32x4 acc[4][4])
{
    const int tid  = threadIdx.x;
    const int lane = tid & 63, wave = tid >> 6;
    const int g = lane >> 4, fr = lane & 15;
    const int swl = (fr & 7) << 3;
    const int sub = lane >> 3;
    const int kcs = ((lane & 7) ^ sub) << 3;
    const int wr = wave >> 1, wc = wave & 1;

    const ushort* asrc[4];
    const ushort* bsrc[4];
#pragma unroll
    for (int i = 0; i < 4; ++i) {
        int row = (wave * 4 + i) * 8 + sub;
        int ar = tileM + row; if (ar > count - 1) ar = count - 1;
        int grow = gather ? gather[ar] : ar;
        asrc[i] = A  + (size_t)grow * K + kcs;
        bsrc[i] = BT + (size_t)(tileN + row) * K + kcs;
    }

    const int NT = K >> 6;
    for (int t = 0; t < NT; ++t) {
#pragma unroll
        for (int i = 0; i < 4; ++i) {
            int chunk = wave * 4 + i;
            __builtin_amdgcn_global_load_lds(
                (const __attribute__((address_space(1))) void*)(asrc[i] + t * 64),
                (__attribute__((address_space(3))) void*)(lds + chunk * 512),
                16, 0, 0);
            __builtin_amdgcn_global_load_lds(
                (const __attribute__((address_space(1))) void*)(bsrc[i] + t * 64),
                (__attribute__((address_space(3))) void*)(lds + 8192 + chunk * 512),
                16, 0, 0);
        }
        __syncthreads();
#pragma unroll
        for (int kk = 0; kk < 2; ++kk) {
            int koff = (kk * 32 + g * 8) ^ swl;
            short8 a[4], b[4];
#pragma unroll
            for (int m = 0; m < 4; ++m) {
                int row = wr * 64 + m * 16 + fr;
                a[m] = *(const short8*)&lds[row * 64 + koff];
            }
#pragma unroll
            for (int n = 0; n < 4; ++n) {
                int col = wc * 64 + n * 16 + fr;
                b[n] = *(const short8*)&lds[8192 + col * 64 + koff];
            }
#pragma unroll
            for (int m = 0; m < 4; ++m)
#pragma unroll
                for (int n = 0; n < 4; ++n)
                    acc[m][n] = __builtin_amdgcn_mfma_f32_16x16x32_bf16(
                        a[m], b[n], acc[m][n], 0, 0, 0);
        }
        __syncthreads();
    }
}

// ===== GEMM2 inner: 256x256, BK=64, 8 waves, dbuf 128 KiB, counted vmcnt(8) (R11) =====
__device__ __forceinline__ void mma256(
    const ushort* __restrict__ A, int count,
    const ushort* __restrict__ BT, int K, int tileM, int tileN,
    ushort* lds, f32x4 acc[8][4])
{
    const int tid  = threadIdx.x;
    const int lane = tid & 63, wave = tid >> 6;       // 8 waves
    const int wr = wave >> 2, wc = wave & 3;          // 2M x 4N
    const int g = lane >> 4, fr = lane & 15;
    const int swl = (fr & 7) << 3;
    const int sub = lane >> 3;
    const int kcs = ((lane & 7) ^ sub) << 3;

    const ushort* asrc[4];
    const ushort* bsrc[4];
#pragma unroll
    for (int i = 0; i < 4; ++i) {
        int row = (wave * 4 + i) * 8 + sub;           // 32 chunks cover 256 rows
        int ar = tileM + row; if (ar > count - 1) ar = count - 1;
        asrc[i] = A  + (size_t)ar * K + kcs;
        bsrc[i] = BT + (size_t)(tileN + row) * K + kcs;
    }

    auto STAGE = [&](int buf, int t) {
        ushort* base = lds + buf * 32768;             // A at +0, B at +16384 (elems)
#pragma unroll
        for (int i = 0; i < 4; ++i) {
            int chunk = wave * 4 + i;
            __builtin_amdgcn_global_load_lds(
                (const __attribute__((address_space(1))) void*)(asrc[i] + t * 64),
                (__attribute__((address_space(3))) void*)(base + chunk * 512),
                16, 0, 0);
            __builtin_amdgcn_global_load_lds(
                (const __attribute__((address_space(1))) void*)(bsrc[i] + t * 64),
                (__attribute__((address_space(3))) void*)(base + 16384 + chunk * 512),
                16, 0, 0);
        }
    };

    auto COMPUTE = [&](int buf) {
        const ushort* A_s = lds + buf * 32768;
        const ushort* B_s = A_s + 16384;
#pragma unroll
        for (int kk = 0; kk < 2; ++kk) {
            int koff = (kk * 32 + g * 8) ^ swl;
            short8 a[8], b[4];
#pragma unroll
            for (int m = 0; m < 8; ++m) {
                int row = wr * 128 + m * 16 + fr;
                a[m] = *(const short8*)&A_s[row * 64 + koff];
            }
#pragma unroll
            for (int n = 0; n < 4; ++n) {
                int col = wc * 64 + n * 16 + fr;
                b[n] = *(const short8*)&B_s[col * 64 + koff];
            }
#pragma unroll
            for (int m = 0; m < 8; ++m)
#pragma unroll
                for (int n = 0; n < 4; ++n)
                    acc[m][n] = __builtin_amdgcn_mfma_f32_16x16x32_bf16(
                        a[m], b[n], acc[m][n], 0, 0, 0);
        }
    };

    const int NT = K >> 6;
    STAGE(0, 0);
    for (int t = 0; t < NT; ++t) {
        int cur = t & 1;
        if (t + 1 < NT) {
            STAGE(cur ^ 1, t + 1);
            asm volatile("s_waitcnt vmcnt(8)" ::: "memory");
        } else {
            asm volatile("s_waitcnt vmcnt(0)" ::: "memory");
        }
        __builtin_amdgcn_s_barrier();
        asm volatile("" ::: "memory");
        COMPUTE(cur);
        asm volatile("" ::: "memory");
        __builtin_amdgcn_s_barrier();
    }
}

// ------- persistent GEMM1, XCD-partitioned atomic queues (R18 proven): partition =
//         blockIdx&7 (round-robin block->XCD map); each partition owns a contiguous
//         queue slice so its 256 KB B panels stay resident in that XCD's L2. -------
__global__ __launch_bounds__(256, 4)
void gemm1_kernel(const ushort* __restrict__ xb,
                  const ushort* __restrict__ ew1T, const ushort* __restrict__ sw1T,
                  const float* __restrict__ eb1, const float* __restrict__ sb1,
                  const int* __restrict__ ids, const int* __restrict__ cnt,
                  const int* __restrict__ offs,
                  const int* __restrict__ q1, const int* __restrict__ nq,
                  int* __restrict__ qc, ushort* __restrict__ h)
{
    __shared__ ushort lds[16384];
    __shared__ int s_it;
    const int nit = nq[0];
    const int part = blockIdx.x & 7;
    const int qs = (part * nit) >> 3, qe = ((part + 1) * nit) >> 3;
    const int lane = threadIdx.x & 63, wave = threadIdx.x >> 6;
    const int wr = wave >> 1, wc = wave & 1, g = lane >> 4, fr = lane & 15;

    for (;;) {
        if (threadIdx.x == 0) s_it = qs + atomicAdd(&qc[part], 1);
        __syncthreads();
        int it = s_it;
        if (it >= qe) break;
        int item = q1[it];
        int z = item >> 16, mt = (item >> 8) & 255, nt = item & 255;
        int count, hbase;
        const ushort* BT; const float* bias; const int* gather;
        if (z < NE) {
            count  = cnt[z];
            BT     = ew1T + (size_t)z * HID * DIM;
            bias   = eb1 + z * HID;
            gather = ids + z * T_TOK;
            hbase  = T_TOK + offs[z];
        } else {
            count = T_TOK; BT = sw1T; bias = sb1; gather = nullptr; hbase = 0;
        }
        int tileM = mt * 128, tileN = nt * 128;

        f32x4 acc[4][4];
#pragma unroll
        for (int m = 0; m < 4; ++m)
#pragma unroll
            for (int n = 0; n < 4; ++n) acc[m][n] = (f32x4){0.f, 0.f, 0.f, 0.f};

        mma_tile(xb, gather, count, BT, DIM, tileM, tileN, lds, acc);

#pragma unroll
        for (int n = 0; n < 4; ++n) {
            int col = tileN + wc * 64 + n * 16 + fr;
            float bc = bias[col];
#pragma unroll
            for (int m = 0; m < 4; ++m) {
#pragma unroll
                for (int i = 0; i < 4; ++i) {
                    int row = tileM + wr * 64 + m * 16 + g * 4 + i;
                    if (row < count)
                        h[(size_t)(hbase + row) * HID + col] =
                            f2bf(gelu_fast(acc[m][n][i] + bc));
                }
            }
        }
    }
}

// ------- persistent GEMM2 (grid-stride, R11 proven), atomic-free stores:
//         shared -> out f32 (covers all); experts -> eo f32 = w*(y+b) -------
__global__ __launch_bounds__(512, 2)
void gemm2_kernel(const ushort* __restrict__ h,
                  const ushort* __restrict__ ew2T, const ushort* __restrict__ sw2T,
                  const float* __restrict__ eb2, const float* __restrict__ sb2,
                  const float* __restrict__ wts,
                  const int* __restrict__ cnt, const int* __restrict__ offs,
                  const int* __restrict__ q2, const int* __restrict__ n2,
                  float* __restrict__ eo, float* __restrict__ out)
{
    extern __shared__ ushort lds[];
    const int nit = *n2;
    const int lane = threadIdx.x & 63, wave = threadIdx.x >> 6;
    const int wr = wave >> 2, wc = wave & 3, g = lane >> 4, fr = lane & 15;

    for (int it = blockIdx.x; it < nit; it += gridDim.x) {
        int item = q2[it];
        int z = item >> 16, mt = (item >> 8) & 255, nt = item & 255;
        int count;
        const ushort* BT; const float* bias; const float* tw; float* dst;
        const ushort* Arows;
        if (z < NE) {
            count = cnt[z];
            BT    = ew2T + (size_t)z * DIM * HID;
            bias  = eb2 + z * DIM;
            tw    = wts + z * T_TOK;
            Arows = h + (size_t)(T_TOK + offs[z]) * HID;
            dst   = eo + (size_t)offs[z] * DIM;
        } else {
            count = T_TOK; BT = sw2T; bias = sb2; tw = nullptr;
            Arows = h;
            dst   = out;
        }
        int tileM = mt * 256, tileN = nt * 256;

        f32x4 acc[8][4];
#pragma unroll
        for (int m = 0; m < 8; ++m)
#pragma unroll
            for (int n = 0; n < 4; ++n) acc[m][n] = (f32x4){0.f, 0.f, 0.f, 0.f};

        mma256(Arows, count, BT, HID, tileM, tileN, lds, acc);

#pragma unroll
        for (int m = 0; m < 8; ++m) {
#pragma unroll
            for (int i = 0; i < 4; ++i) {
                int row = tileM + wr * 128 + m * 16 + g * 4 + i;
                if (row < count) {
                    float w = tw ? tw[row] : 1.0f;
#pragma unroll
                    for (int n = 0; n < 4; ++n) {
                        int col = tileN + wc * 64 + n * 16 + fr;
                        dst[(size_t)row * DIM + col] = w * (acc[m][n][i] + bias[col]);
                    }
                }
            }
        }
        __syncthreads();   // LDS safe for next item's staging
    }
}

// ------- combine: out[t] += eo[slot1(t)] + eo[slot2(t)]  (w already folded) -------
__global__ void combine_kernel(const float* __restrict__ eo, const int* __restrict__ te,
                               const int* __restrict__ tp, const int* __restrict__ offs,
                               float* __restrict__ out)
{
    int t = blockIdx.x;
    int s1 = offs[te[2 * t]]     + tp[2 * t];
    int s2 = offs[te[2 * t + 1]] + tp[2 * t + 1];
    int d = threadIdx.x * 4;
    float4 a = *(const float4*)(out + (size_t)t * DIM + d);
    float4 b = *(const float4*)(eo + (size_t)s1 * DIM + d);
    float4 c = *(const float4*)(eo + (size_t)s2 * DIM + d);
    a.x += b.x + c.x; a.y += b.y + c.y; a.z += b.z + c.z; a.w += b.w + c.w;
    *(float4*)(out + (size_t)t * DIM + d) = a;
}

extern "C" void kernel_launch(void* const* d_in, const int* in_sizes, int n_in,
                              void* d_out, int out_size, void* d_ws, size_t ws_size,
                              hipStream_t stream)
{
    const float* x   = (const float*)d_in[0];
    const float* rw  = (const float*)d_in[1];
    const float* rb  = (const float*)d_in[2];
    const float* sw1 = (const float*)d_in[3];
    const float* sb1 = (const float*)d_in[4];
    const float* sw2 = (const float*)d_in[5];
    const float* sb2 = (const float*)d_in[6];
    const float* ew1 = (const float*)d_in[7];
    const float* eb1 = (const float*)d_in[8];
    const float* ew2 = (const float*)d_in[9];
    const float* eb2 = (const float*)d_in[10];
    float* out = (float*)d_out;

    char* p = (char*)d_ws;
    ushort* xb   = (ushort*)p;  p += (size_t)T_TOK * DIM * 2;
    ushort* sw1T = (ushort*)p;  p += (size_t)HID * DIM * 2;
    ushort* sw2T = (ushort*)p;  p += (size_t)DIM * HID * 2;
    ushort* ew1T = (ushort*)p;  p += (size_t)NE * HID * DIM * 2;
    ushort* ew2T = (ushort*)p;  p += (size_t)NE * DIM * HID * 2;
    ushort* hbuf = (ushort*)p;  p += (size_t)(3 * T_TOK) * HID * 2;
    float*  eo   = (float*)p;   p += (size_t)(2 * T_TOK) * DIM * 4;
    int*    ids  = (int*)p;     p += (size_t)NE * T_TOK * 4;
    float*  wts  = (float*)p;   p += (size_t)NE * T_TOK * 4;
    int*    te   = (int*)p;     p += (size_t)2 * T_TOK * 4;
    int*    tp   = (int*)p;     p += (size_t)2 * T_TOK * 4;
    int*    cnt  = (int*)p;     p += 256;
    int*    offs = (int*)p;     p += 256;
    int*    q1   = (int*)p;     p += 16384;  // 4096 ints
    int*    q2   = (int*)p;     p += 8192;   // 2048 ints
    int*    nq   = (int*)p;     p += 256;    // n1,n2,-,-, 8 partition cursors at +8

    hipFuncSetAttribute((const void*)gemm2_kernel,
                        hipFuncAttributeMaxDynamicSharedMemorySize, 131072);

    hipMemsetAsync(cnt, 0, 256, stream);

    // R17 launch order (router first) — R18's transpose-first reorder cost ~18 us.
    router_kernel<<<dim3(T_TOK / 4), 256, 0, stream>>>(x, rw, rb, cnt, ids, wts, te, tp, xb);
    transpose_conv18<<<dim3(32, 16, 18), 256, 0, stream>>>(
        ew1, sw1, ew2, sw2, ew1T, sw1T, ew2T, sw2T);
    build_queue<<<dim3(1), 64, 0, stream>>>(cnt, offs, q1, q2, nq);
    gemm1_kernel<<<dim3(1024), 256, 0, stream>>>(
        xb, ew1T, sw1T, eb1, sb1, ids, cnt, offs, q1, nq, nq + 8, hbuf);
    gemm2_kernel<<<dim3(256), 512, 131072, stream>>>(
        hbuf, ew2T, sw2T, eb2, sb2, wts, cnt, offs, q2, nq + 1, eo, out);
    combine_kernel<<<dim3(T_TOK), 256, 0, stream>>>(eo, te, tp, offs, out);
}

// Round 20
// 343.792 us; speedup vs baseline: 1.0746x; 1.0746x over previous
//
#include <hip/hip_runtime.h>

#define DIM   1024
#define HID   2048
#define NE    8
#define T_TOK 4096

typedef __attribute__((ext_vector_type(8))) short short8;
typedef __attribute__((ext_vector_type(4))) float f32x4;

__device__ __forceinline__ ushort f2bf(float f) {
    union { float f; unsigned u; } v; v.f = f;
    unsigned r = v.u + 0x7FFFu + ((v.u >> 16) & 1u);   // RNE
    return (ushort)(r >> 16);
}

// tanh-form gelu, x - x/(e+1) (inf-safe); dev from erf-gelu ~1e-3, absorbed by bf16.
__device__ __forceinline__ float gelu_fast(float x) {
    float t = x * x;
    float u = x * (1.0f + 0.044715f * t);
    float e = exp2f(2.3020585f * u);
    return x - x / (e + 1.0f);
}

// ======= fused prologue: z 0..17 = weight transpose+convert; z=18 = router =======
// transpose (verified R13/R15): in[R][C] f32 -> out[C][R] bf16, 64x64 tiles.
// router (verified R11+): top-2 of softmax(x@rw+rb) renormalized, + x->bf16;
//   512 blocks x 8 tokens (2 tokens per wave, sequential). Fully independent of
//   the transpose work — fusing removes one launch and hides router's ~10us.
__global__ __launch_bounds__(256)
void prologue_kernel(const float* __restrict__ x, const float* __restrict__ rw,
                     const float* __restrict__ rb, int* __restrict__ cnt,
                     int* __restrict__ ids, float* __restrict__ wts,
                     int* __restrict__ te, int* __restrict__ tp,
                     ushort* __restrict__ xb,
                     const float* __restrict__ ew1, const float* __restrict__ sw1,
                     const float* __restrict__ ew2, const float* __restrict__ sw2,
                     ushort* __restrict__ ew1T, ushort* __restrict__ sw1T,
                     ushort* __restrict__ ew2T, ushort* __restrict__ sw2T)
{
    int z = blockIdx.z;
    if (z == 18) {
        // ---------------- router ----------------
        int bid  = blockIdx.y * 32 + blockIdx.x;       // 0..511
        int wave = threadIdx.x >> 6;
        int lane = threadIdx.x & 63;
#pragma unroll
        for (int rep = 0; rep < 2; ++rep) {
            int t = bid * 8 + rep * 4 + wave;
            const float* xr = x + (size_t)t * DIM;
            ushort* xo = xb + (size_t)t * DIM;
            float acc[NE];
#pragma unroll
            for (int e = 0; e < NE; ++e) acc[e] = 0.f;
            {
                int d0 = lane * 16;
                float v[16];
#pragma unroll
                for (int j = 0; j < 16; j += 4) {
                    float4 f = *(const float4*)(xr + d0 + j);
                    v[j] = f.x; v[j+1] = f.y; v[j+2] = f.z; v[j+3] = f.w;
                }
                short8 o0, o1;
#pragma unroll
                for (int j = 0; j < 8; ++j) {
                    o0[j] = (short)f2bf(v[j]); o1[j] = (short)f2bf(v[8+j]);
                }
                *(short8*)(xo + d0)     = o0;
                *(short8*)(xo + d0 + 8) = o1;
#pragma unroll
                for (int j = 0; j < 16; ++j) {
#pragma unroll
                    for (int e = 0; e < NE; ++e) acc[e] += v[j] * rw[(d0 + j) * NE + e];
                }
            }
#pragma unroll
            for (int e = 0; e < NE; ++e) {
#pragma unroll
                for (int off = 32; off; off >>= 1) acc[e] += __shfl_xor(acc[e], off);
            }
            if (lane == 0) {
                float l[NE];
#pragma unroll
                for (int e = 0; e < NE; ++e) l[e] = acc[e] + rb[e];
                int i1 = 0;
#pragma unroll
                for (int e = 1; e < NE; ++e) if (l[e] > l[i1]) i1 = e;
                int i2 = (i1 == 0) ? 1 : 0;
#pragma unroll
                for (int e = 0; e < NE; ++e) if (e != i1 && l[e] > l[i2]) i2 = e;
                float p2 = __expf(l[i2] - l[i1]);      // p1 = 1
                float w1 = 1.0f / (1.0f + p2);
                float w2 = p2 / (1.0f + p2);
                int pos1 = atomicAdd(&cnt[i1], 1);
                ids[i1 * T_TOK + pos1] = t; wts[i1 * T_TOK + pos1] = w1;
                te[2 * t] = i1; tp[2 * t] = pos1;
                int pos2 = atomicAdd(&cnt[i2], 1);
                ids[i2 * T_TOK + pos2] = t; wts[i2 * T_TOK + pos2] = w2;
                te[2 * t + 1] = i2; tp[2 * t + 1] = pos2;
            }
        }
        return;
    }
    // ---------------- transpose+convert ----------------
    __shared__ float tile[64][65];
    const float* in; ushort* out; int R, C, bx, by;
    if (z < 9) {
        R = DIM; C = HID; bx = blockIdx.x; by = blockIdx.y;              // 32 x 16
        in  = (z < 8) ? ew1  + (size_t)z * R * C : sw1;
        out = (z < 8) ? ew1T + (size_t)z * R * C : sw1T;
    } else {
        int zz = z - 9;
        R = HID; C = DIM;
        bx = blockIdx.x & 15; by = blockIdx.y * 2 + (blockIdx.x >> 4);   // 16 x 32
        in  = (zz < 8) ? ew2  + (size_t)zz * R * C : sw2;
        out = (zz < 8) ? ew2T + (size_t)zz * R * C : sw2T;
    }
    int c0 = bx * 64, r0 = by * 64;
    int t = threadIdx.x;
    int lr = t >> 4, lc4 = (t & 15) * 4;
#pragma unroll
    for (int p = 0; p < 4; ++p) {
        float4 f = *(const float4*)(in + (size_t)(r0 + p * 16 + lr) * C + c0 + lc4);
        tile[p * 16 + lr][lc4]     = f.x;
        tile[p * 16 + lr][lc4 + 1] = f.y;
        tile[p * 16 + lr][lc4 + 2] = f.z;
        tile[p * 16 + lr][lc4 + 3] = f.w;
    }
    __syncthreads();
    int oc = t >> 3, rg = (t & 7) * 8;
#pragma unroll
    for (int p = 0; p < 2; ++p) {
        int c = p * 32 + oc;
        short8 o;
#pragma unroll
        for (int j = 0; j < 8; ++j) o[j] = (short)f2bf(tile[rg + j][c]);
        *(short8*)(out + (size_t)(c0 + c) * R + r0 + rg) = o;
    }
}

// ------- build offsets + work queues (R17): q1 = 128x128 mt-outer (gemm1),
//         q2 = 256x256 mt-outer (gemm2). item = (z<<16)|(mt<<8)|nt. -------
__global__ void build_queue(const int* __restrict__ cnt, int* __restrict__ offs,
                            int* __restrict__ q1, int* __restrict__ q2,
                            int* __restrict__ nq) {
    if (threadIdx.x != 0) return;
    int s = 0;
    for (int e = 0; e < NE; ++e) { offs[e] = s; s += cnt[e]; }
    int k1 = 0, k2 = 0;
    for (int z = 0; z <= NE; ++z) {
        int c = (z < NE) ? cnt[z] : T_TOK;
        int mts1 = (c + 127) >> 7;
        for (int mt = 0; mt < mts1; ++mt)
            for (int nt = 0; nt < HID / 128; ++nt)
                q1[k1++] = (z << 16) | (mt << 8) | nt;
        int mts2 = (c + 255) >> 8;
        for (int mt = 0; mt < mts2; ++mt)
            for (int nt = 0; nt < DIM / 256; ++nt)
                q2[k2++] = (z << 16) | (mt << 8) | nt;
    }
    nq[0] = k1; nq[1] = k2;
    nq[2] = 0;  nq[3] = 0;      // queue cursors
}

// ===== GEMM1 inner: m97 structure, 128x128, BK=64, 4 waves, 32 KiB single-buffer =====
__device__ __forceinline__ void mma_tile(
    const ushort* __restrict__ A, const int* __restrict__ gather, int count,
    const ushort* __restrict__ BT, int K, int tileM, int tileN,
    ushort* lds, f32x4 acc[4][4])
{
    const int tid  = threadIdx.x;
    const int lane = tid & 63, wave = tid >> 6;
    const int g = lane >> 4, fr = lane & 15;
    const int swl = (fr & 7) << 3;
    const int sub = lane >> 3;
    const int kcs = ((lane & 7) ^ sub) << 3;
    const int wr = wave >> 1, wc = wave & 1;

    const ushort* asrc[4];
    const ushort* bsrc[4];
#pragma unroll
    for (int i = 0; i < 4; ++i) {
        int row = (wave * 4 + i) * 8 + sub;
        int ar = tileM + row; if (ar > count - 1) ar = count - 1;
        int grow = gather ? gather[ar] : ar;
        asrc[i] = A  + (size_t)grow * K + kcs;
        bsrc[i] = BT + (size_t)(tileN + row) * K + kcs;
    }

    const int NT = K >> 6;
    for (int t = 0; t < NT; ++t) {
#pragma unroll
        for (int i = 0; i < 4; ++i) {
            int chunk = wave * 4 + i;
            __builtin_amdgcn_global_load_lds(
                (const __attribute__((address_space(1))) void*)(asrc[i] + t * 64),
                (__attribute__((address_space(3))) void*)(lds + chunk * 512),
                16, 0, 0);
            __builtin_amdgcn_global_load_lds(
                (const __attribute__((address_space(1))) void*)(bsrc[i] + t * 64),
                (__attribute__((address_space(3))) void*)(lds + 8192 + chunk * 512),
                16, 0, 0);
        }
        __syncthreads();
#pragma unroll
        for (int kk = 0; kk < 2; ++kk) {
            int koff = (kk * 32 + g * 8) ^ swl;
            short8 a[4], b[4];
#pragma unroll
            for (int m = 0; m < 4; ++m) {
                int row = wr * 64 + m * 16 + fr;
                a[m] = *(const short8*)&lds[row * 64 + koff];
            }
#pragma unroll
            for (int n = 0; n < 4; ++n) {
                int col = wc * 64 + n * 16 + fr;
                b[n] = *(const short8*)&lds[8192 + col * 64 + koff];
            }
#pragma unroll
            for (int m = 0; m < 4; ++m)
#pragma unroll
                for (int n = 0; n < 4; ++n)
                    acc[m][n] = __builtin_amdgcn_mfma_f32_16x16x32_bf16(
                        a[m], b[n], acc[m][n], 0, 0, 0);
        }
        __syncthreads();
    }
}

// ===== GEMM2 inner: 256x256, BK=64, 8 waves, dbuf 128 KiB, counted vmcnt(8) (R11) =====
__device__ __forceinline__ void mma256(
    const ushort* __restrict__ A, int count,
    const ushort* __restrict__ BT, int K, int tileM, int tileN,
    ushort* lds, f32x4 acc[8][4])
{
    const int tid  = threadIdx.x;
    const int lane = tid & 63, wave = tid >> 6;       // 8 waves
    const int wr = wave >> 2, wc = wave & 3;          // 2M x 4N
    const int g = lane >> 4, fr = lane & 15;
    const int swl = (fr & 7) << 3;
    const int sub = lane >> 3;
    const int kcs = ((lane & 7) ^ sub) << 3;

    const ushort* asrc[4];
    const ushort* bsrc[4];
#pragma unroll
    for (int i = 0; i < 4; ++i) {
        int row = (wave * 4 + i) * 8 + sub;           // 32 chunks cover 256 rows
        int ar = tileM + row; if (ar > count - 1) ar = count - 1;
        asrc[i] = A  + (size_t)ar * K + kcs;
        bsrc[i] = BT + (size_t)(tileN + row) * K + kcs;
    }

    auto STAGE = [&](int buf, int t) {
        ushort* base = lds + buf * 32768;             // A at +0, B at +16384 (elems)
#pragma unroll
        for (int i = 0; i < 4; ++i) {
            int chunk = wave * 4 + i;
            __builtin_amdgcn_global_load_lds(
                (const __attribute__((address_space(1))) void*)(asrc[i] + t * 64),
                (__attribute__((address_space(3))) void*)(base + chunk * 512),
                16, 0, 0);
            __builtin_amdgcn_global_load_lds(
                (const __attribute__((address_space(1))) void*)(bsrc[i] + t * 64),
                (__attribute__((address_space(3))) void*)(base + 16384 + chunk * 512),
                16, 0, 0);
        }
    };

    auto COMPUTE = [&](int buf) {
        const ushort* A_s = lds + buf * 32768;
        const ushort* B_s = A_s + 16384;
#pragma unroll
        for (int kk = 0; kk < 2; ++kk) {
            int koff = (kk * 32 + g * 8) ^ swl;
            short8 a[8], b[4];
#pragma unroll
            for (int m = 0; m < 8; ++m) {
                int row = wr * 128 + m * 16 + fr;
                a[m] = *(const short8*)&A_s[row * 64 + koff];
            }
#pragma unroll
            for (int n = 0; n < 4; ++n) {
                int col = wc * 64 + n * 16 + fr;
                b[n] = *(const short8*)&B_s[col * 64 + koff];
            }
#pragma unroll
            for (int m = 0; m < 8; ++m)
#pragma unroll
                for (int n = 0; n < 4; ++n)
                    acc[m][n] = __builtin_amdgcn_mfma_f32_16x16x32_bf16(
                        a[m], b[n], acc[m][n], 0, 0, 0);
        }
    };

    const int NT = K >> 6;
    STAGE(0, 0);
    for (int t = 0; t < NT; ++t) {
        int cur = t & 1;
        if (t + 1 < NT) {
            STAGE(cur ^ 1, t + 1);
            asm volatile("s_waitcnt vmcnt(8)" ::: "memory");
        } else {
            asm volatile("s_waitcnt vmcnt(0)" ::: "memory");
        }
        __builtin_amdgcn_s_barrier();
        asm volatile("" ::: "memory");
        COMPUTE(cur);
        asm volatile("" ::: "memory");
        __builtin_amdgcn_s_barrier();
    }
}

// ------- persistent GEMM1 (atomic queue, R12/R17 proven): h = gelu(X @ W1 + b1) -------
__global__ __launch_bounds__(256, 4)
void gemm1_kernel(const ushort* __restrict__ xb,
                  const ushort* __restrict__ ew1T, const ushort* __restrict__ sw1T,
                  const float* __restrict__ eb1, const float* __restrict__ sb1,
                  const int* __restrict__ ids, const int* __restrict__ cnt,
                  const int* __restrict__ offs,
                  const int* __restrict__ q1, const int* __restrict__ nq,
                  int* __restrict__ qc, ushort* __restrict__ h)
{
    __shared__ ushort lds[16384];
    __shared__ int s_it;
    const int nit = nq[0];
    const int lane = threadIdx.x & 63, wave = threadIdx.x >> 6;
    const int wr = wave >> 1, wc = wave & 1, g = lane >> 4, fr = lane & 15;

    for (;;) {
        if (threadIdx.x == 0) s_it = atomicAdd(qc, 1);
        __syncthreads();
        int it = s_it;
        if (it >= nit) break;
        int item = q1[it];
        int z = item >> 16, mt = (item >> 8) & 255, nt = item & 255;
        int count, hbase;
        const ushort* BT; const float* bias; const int* gather;
        if (z < NE) {
            count  = cnt[z];
            BT     = ew1T + (size_t)z * HID * DIM;
            bias   = eb1 + z * HID;
            gather = ids + z * T_TOK;
            hbase  = T_TOK + offs[z];
        } else {
            count = T_TOK; BT = sw1T; bias = sb1; gather = nullptr; hbase = 0;
        }
        int tileM = mt * 128, tileN = nt * 128;

        f32x4 acc[4][4];
#pragma unroll
        for (int m = 0; m < 4; ++m)
#pragma unroll
            for (int n = 0; n < 4; ++n) acc[m][n] = (f32x4){0.f, 0.f, 0.f, 0.f};

        mma_tile(xb, gather, count, BT, DIM, tileM, tileN, lds, acc);

#pragma unroll
        for (int n = 0; n < 4; ++n) {
            int col = tileN + wc * 64 + n * 16 + fr;
            float bc = bias[col];
#pragma unroll
            for (int m = 0; m < 4; ++m) {
#pragma unroll
                for (int i = 0; i < 4; ++i) {
                    int row = tileM + wr * 64 + m * 16 + g * 4 + i;
                    if (row < count)
                        h[(size_t)(hbase + row) * HID + col] =
                            f2bf(gelu_fast(acc[m][n][i] + bc));
                }
            }
        }
    }
}

// ------- persistent GEMM2 (grid-stride, R11 proven), atomic-free stores:
//         shared -> out f32 (covers all); experts -> eo f32 = w*(y+b) -------
__global__ __launch_bounds__(512, 2)
void gemm2_kernel(const ushort* __restrict__ h,
                  const ushort* __restrict__ ew2T, const ushort* __restrict__ sw2T,
                  const float* __restrict__ eb2, const float* __restrict__ sb2,
                  const float* __restrict__ wts,
                  const int* __restrict__ cnt, const int* __restrict__ offs,
                  const int* __restrict__ q2, const int* __restrict__ n2,
                  float* __restrict__ eo, float* __restrict__ out)
{
    extern __shared__ ushort lds[];
    const int nit = *n2;
    const int lane = threadIdx.x & 63, wave = threadIdx.x >> 6;
    const int wr = wave >> 2, wc = wave & 3, g = lane >> 4, fr = lane & 15;

    for (int it = blockIdx.x; it < nit; it += gridDim.x) {
        int item = q2[it];
        int z = item >> 16, mt = (item >> 8) & 255, nt = item & 255;
        int count;
        const ushort* BT; const float* bias; const float* tw; float* dst;
        const ushort* Arows;
        if (z < NE) {
            count = cnt[z];
            BT    = ew2T + (size_t)z * DIM * HID;
            bias  = eb2 + z * DIM;
            tw    = wts + z * T_TOK;
            Arows = h + (size_t)(T_TOK + offs[z]) * HID;
            dst   = eo + (size_t)offs[z] * DIM;
        } else {
            count = T_TOK; BT = sw2T; bias = sb2; tw = nullptr;
            Arows = h;
            dst   = out;
        }
        int tileM = mt * 256, tileN = nt * 256;

        f32x4 acc[8][4];
#pragma unroll
        for (int m = 0; m < 8; ++m)
#pragma unroll
            for (int n = 0; n < 4; ++n) acc[m][n] = (f32x4){0.f, 0.f, 0.f, 0.f};

        mma256(Arows, count, BT, HID, tileM, tileN, lds, acc);

#pragma unroll
        for (int m = 0; m < 8; ++m) {
#pragma unroll
            for (int i = 0; i < 4; ++i) {
                int row = tileM + wr * 128 + m * 16 + g * 4 + i;
                if (row < count) {
                    float w = tw ? tw[row] : 1.0f;
#pragma unroll
                    for (int n = 0; n < 4; ++n) {
                        int col = tileN + wc * 64 + n * 16 + fr;
                        dst[(size_t)row * DIM + col] = w * (acc[m][n][i] + bias[col]);
                    }
                }
            }
        }
        __syncthreads();   // LDS safe for next item's staging
    }
}

// ------- combine: out[t] += eo[slot1(t)] + eo[slot2(t)]  (w already folded) -------
__global__ void combine_kernel(const float* __restrict__ eo, const int* __restrict__ te,
                               const int* __restrict__ tp, const int* __restrict__ offs,
                               float* __restrict__ out)
{
    int t = blockIdx.x;
    int s1 = offs[te[2 * t]]     + tp[2 * t];
    int s2 = offs[te[2 * t + 1]] + tp[2 * t + 1];
    int d = threadIdx.x * 4;
    float4 a = *(const float4*)(out + (size_t)t * DIM + d);
    float4 b = *(const float4*)(eo + (size_t)s1 * DIM + d);
    float4 c = *(const float4*)(eo + (size_t)s2 * DIM + d);
    a.x += b.x + c.x; a.y += b.y + c.y; a.z += b.z + c.z; a.w += b.w + c.w;
    *(float4*)(out + (size_t)t * DIM + d) = a;
}

extern "C" void kernel_launch(void* const* d_in, const int* in_sizes, int n_in,
                              void* d_out, int out_size, void* d_ws, size_t ws_size,
                              hipStream_t stream)
{
    const float* x   = (const float*)d_in[0];
    const float* rw  = (const float*)d_in[1];
    const float* rb  = (const float*)d_in[2];
    const float* sw1 = (const float*)d_in[3];
    const float* sb1 = (const float*)d_in[4];
    const float* sw2 = (const float*)d_in[5];
    const float* sb2 = (const float*)d_in[6];
    const float* ew1 = (const float*)d_in[7];
    const float* eb1 = (const float*)d_in[8];
    const float* ew2 = (const float*)d_in[9];
    const float* eb2 = (const float*)d_in[10];
    float* out = (float*)d_out;

    char* p = (char*)d_ws;
    ushort* xb   = (ushort*)p;  p += (size_t)T_TOK * DIM * 2;
    ushort* sw1T = (ushort*)p;  p += (size_t)HID * DIM * 2;
    ushort* sw2T = (ushort*)p;  p += (size_t)DIM * HID * 2;
    ushort* ew1T = (ushort*)p;  p += (size_t)NE * HID * DIM * 2;
    ushort* ew2T = (ushort*)p;  p += (size_t)NE * DIM * HID * 2;
    ushort* hbuf = (ushort*)p;  p += (size_t)(3 * T_TOK) * HID * 2;
    float*  eo   = (float*)p;   p += (size_t)(2 * T_TOK) * DIM * 4;
    int*    ids  = (int*)p;     p += (size_t)NE * T_TOK * 4;
    float*  wts  = (float*)p;   p += (size_t)NE * T_TOK * 4;
    int*    te   = (int*)p;     p += (size_t)2 * T_TOK * 4;
    int*    tp   = (int*)p;     p += (size_t)2 * T_TOK * 4;
    int*    cnt  = (int*)p;     p += 256;
    int*    offs = (int*)p;     p += 256;
    int*    q1   = (int*)p;     p += 16384;  // 4096 ints
    int*    q2   = (int*)p;     p += 8192;   // 2048 ints
    int*    nq   = (int*)p;     p += 256;    // n1,n2,qc1,qc2

    hipFuncSetAttribute((const void*)gemm2_kernel,
                        hipFuncAttributeMaxDynamicSharedMemorySize, 131072);

    hipMemsetAsync(cnt, 0, 256, stream);

    // fused router + weight transpose (independent work, one launch)
    prologue_kernel<<<dim3(32, 16, 19), 256, 0, stream>>>(
        x, rw, rb, cnt, ids, wts, te, tp, xb,
        ew1, sw1, ew2, sw2, ew1T, sw1T, ew2T, sw2T);
    build_queue<<<dim3(1), 64, 0, stream>>>(cnt, offs, q1, q2, nq);
    gemm1_kernel<<<dim3(1024), 256, 0, stream>>>(
        xb, ew1T, sw1T, eb1, sb1, ids, cnt, offs, q1, nq, nq + 2, hbuf);
    gemm2_kernel<<<dim3(256), 512, 131072, stream>>>(
        hbuf, ew2T, sw2T, eb2, sb2, wts, cnt, offs, q2, nq + 1, eo, out);
    combine_kernel<<<dim3(T_TOK), 256, 0, stream>>>(eo, te, tp, offs, out);
}